// Round 1
// baseline (1345.578 us; speedup 1.0000x reference)
//
#include <hip/hip_runtime.h>

static constexpr int H = 128, W = 128, HW = H * W;

__device__ __forceinline__ float silu_f(float v) {
    return v / (1.f + __expf(-v));
}

// ---------------- weight transpose: [cout][cin][3][3] -> [cin][ky][kx][cout] ----------------
__global__ void wtrans_k(const float* __restrict__ w, float* __restrict__ wt, int Cin, int Cout) {
    int n = Cout * Cin * 9;
    for (int idx = blockIdx.x * blockDim.x + threadIdx.x; idx < n; idx += gridDim.x * blockDim.x) {
        int cout = idx / (Cin * 9);
        int rem  = idx - cout * (Cin * 9);
        int cin  = rem / 9;
        int k    = rem - cin * 9;
        wt[(cin * 9 + k) * Cout + cout] = w[idx];
    }
}

// ---------------- build x = concat(image, r, cos(phi), sin(phi)) ----------------
__global__ void build_x_k(const float* __restrict__ img, float* __restrict__ x, int Bc) {
    int n = blockIdx.x * 256 + threadIdx.x;
    if (n >= Bc * HW) return;
    int b = n >> 14;
    int rem = n & (HW - 1);
    int i = rem >> 7;
    int j = rem & 127;
    float X = -1.f + 2.f * j / 127.f;
    float Y = -1.f + 2.f * i / 127.f;
    float r = sqrtf(X * X + Y * Y);
    float c, s;
    if (r > 0.f) { c = X / r; s = Y / r; } else { c = 1.f; s = 0.f; }
    float* base = x + (size_t)b * 4 * HW + rem;
    base[0]      = img[n];
    base[HW]     = r;
    base[2 * HW] = c;
    base[3 * HW] = s;
}

// ---------------- direct 3x3 conv, pad=1 (zero), 2 px per thread ----------------
template <int Cin, int Cout>
__global__ __launch_bounds__(256) void conv3x3_k(
    const float* __restrict__ in, const float* __restrict__ wt,
    const float* __restrict__ bias, float* __restrict__ out) {
    const int tid = threadIdx.x;
    const int x0  = (tid & 63) * 2;
    const int y   = blockIdx.x * 4 + (tid >> 6);
    const int b   = blockIdx.y;
    const float* inb = in + (size_t)b * Cin * HW;

    float acc0[Cout], acc1[Cout];
#pragma unroll
    for (int c = 0; c < Cout; c++) { float bv = bias[c]; acc0[c] = bv; acc1[c] = bv; }

    for (int cin = 0; cin < Cin; ++cin) {
        const float* p = inb + cin * HW;
#pragma unroll
        for (int ky = 0; ky < 3; ++ky) {
            int yy = y + ky - 1;
            float v0, v1, v2, v3;
            if (yy < 0 || yy >= H) {
                v0 = v1 = v2 = v3 = 0.f;
            } else {
                const float* row = p + yy * W;
                v0 = (x0 > 0) ? row[x0 - 1] : 0.f;
                v1 = row[x0];
                v2 = row[x0 + 1];
                v3 = (x0 + 2 < W) ? row[x0 + 2] : 0.f;
            }
            const float* wrow = wt + (cin * 9 + ky * 3) * Cout;
#pragma unroll
            for (int c = 0; c < Cout; c++) {
                float w0 = wrow[c];
                float w1 = wrow[Cout + c];
                float w2 = wrow[2 * Cout + c];
                acc0[c] = fmaf(w0, v0, acc0[c]);
                acc0[c] = fmaf(w1, v1, acc0[c]);
                acc0[c] = fmaf(w2, v2, acc0[c]);
                acc1[c] = fmaf(w0, v1, acc1[c]);
                acc1[c] = fmaf(w1, v2, acc1[c]);
                acc1[c] = fmaf(w2, v3, acc1[c]);
            }
        }
    }
    float* ob = out + (size_t)b * Cout * HW + y * W + x0;
#pragma unroll
    for (int c = 0; c < Cout; c++) {
        *reinterpret_cast<float2*>(ob + (size_t)c * HW) = make_float2(acc0[c], acc1[c]);
    }
}

// ---------------- GroupNorm + SiLU, in place. one block per (b, group) ----------------
template <int C, int G>
__global__ __launch_bounds__(256) void gn_silu_k(float* __restrict__ x,
                                                 const float* __restrict__ gamma,
                                                 const float* __restrict__ beta) {
    constexpr int Cg = C / G;
    const int b = blockIdx.y, g = blockIdx.x;
    float* base = x + ((size_t)b * C + g * Cg) * HW;
    const int n4 = Cg * HW / 4;
    const int tid = threadIdx.x;

    float s = 0.f, s2 = 0.f;
    const float4* b4 = reinterpret_cast<const float4*>(base);
    for (int i = tid; i < n4; i += 256) {
        float4 v = b4[i];
        s  += v.x + v.y + v.z + v.w;
        s2 += v.x * v.x + v.y * v.y + v.z * v.z + v.w * v.w;
    }
#pragma unroll
    for (int off = 32; off > 0; off >>= 1) {
        s  += __shfl_down(s, off);
        s2 += __shfl_down(s2, off);
    }
    __shared__ float ps[4], ps2[4];
    __shared__ float smu, srs;
    int lane = tid & 63, wid = tid >> 6;
    if (lane == 0) { ps[wid] = s; ps2[wid] = s2; }
    __syncthreads();
    if (tid == 0) {
        float ts  = ps[0] + ps[1] + ps[2] + ps[3];
        float ts2 = ps2[0] + ps2[1] + ps2[2] + ps2[3];
        float inv = 1.f / (float)(Cg * HW);
        float mu  = ts * inv;
        float var = ts2 * inv - mu * mu;
        smu = mu;
        srs = rsqrtf(var + 1e-5f);
    }
    __syncthreads();
    float mu = smu, rs = srs;
    float4* o4 = reinterpret_cast<float4*>(base);
    for (int i = tid; i < n4; i += 256) {
        int c = g * Cg + (i >> 12);  // 4096 float4 per channel
        float a  = gamma[c] * rs;
        float bb = beta[c] - mu * a;
        float4 v = b4[i];
        v.x = silu_f(fmaf(v.x, a, bb));
        v.y = silu_f(fmaf(v.y, a, bb));
        v.z = silu_f(fmaf(v.z, a, bb));
        v.w = silu_f(fmaf(v.w, a, bb));
        o4[i] = v;
    }
}

// ---------------- fused 1x1 convs -> k, psi ----------------
__global__ void psik_k(const float* __restrict__ h3, const float* __restrict__ p2,
                       const float* __restrict__ kw4, const float* __restrict__ kb4,
                       const float* __restrict__ pw3, const float* __restrict__ pb3,
                       float* __restrict__ outk, float* __restrict__ outpsi, int Bc) {
    int n = blockIdx.x * 256 + threadIdx.x;
    if (n >= Bc * HW) return;
    int b = n >> 14;
    int rem = n & (HW - 1);
    int i = rem >> 7;
    int j = rem & 127;
    const float* hb = h3 + (size_t)b * 16 * HW + rem;
    const float* pb = p2 + (size_t)b * 16 * HW + rem;
    float dk = kb4[0], dp = pb3[0];
#pragma unroll
    for (int c = 0; c < 16; c++) {
        dk = fmaf(kw4[c], hb[(size_t)c * HW], dk);
        dp = fmaf(pw3[c], pb[(size_t)c * HW], dp);
    }
    float k   = 0.5f * (1.f + 0.3f * tanhf(dk));
    float psr = 0.05f * tanhf(dp);
    float X = -1.f + 2.f * j / 127.f;
    float Y = -1.f + 2.f * i / 127.f;
    float r = sqrtf(X * X + Y * Y);
    outk[n]   = k;
    outpsi[n] = fmaf(k, r, psr);
}

// ---------------- separable gaussian blur, reflect padding ----------------
static __device__ __constant__ float GW0 = 0.40261994689423467f;
static __device__ __constant__ float GW1 = 0.24420134200323348f;
static __device__ __constant__ float GW2 = 0.05448868454964433f;

__global__ void blur_h_k(const float* __restrict__ in, float* __restrict__ out, int Bc) {
    int n = blockIdx.x * 256 + threadIdx.x;
    if (n >= Bc * HW) return;
    int j = n & 127;
    const float* row = in + (n - j);
    int jm2 = j - 2; jm2 = jm2 < 0 ? -jm2 : jm2;
    int jm1 = j - 1; jm1 = jm1 < 0 ? -jm1 : jm1;
    int jp1 = j + 1; jp1 = jp1 > 127 ? 254 - jp1 : jp1;
    int jp2 = j + 2; jp2 = jp2 > 127 ? 254 - jp2 : jp2;
    out[n] = GW2 * (row[jm2] + row[jp2]) + GW1 * (row[jm1] + row[jp1]) + GW0 * row[j];
}

__global__ void blur_v_k(const float* __restrict__ in, float* __restrict__ out, int Bc) {
    int n = blockIdx.x * 256 + threadIdx.x;
    if (n >= Bc * HW) return;
    int rem = n & (HW - 1);
    int i = rem >> 7;
    int j = rem & 127;
    const float* pl = in + (n - rem) + j;
    int im2 = i - 2; im2 = im2 < 0 ? -im2 : im2;
    int im1 = i - 1; im1 = im1 < 0 ? -im1 : im1;
    int ip1 = i + 1; ip1 = ip1 > 127 ? 254 - ip1 : ip1;
    int ip2 = i + 2; ip2 = ip2 > 127 ? 254 - ip2 : ip2;
    out[n] = GW2 * (pl[im2 * W] + pl[ip2 * W]) + GW1 * (pl[im1 * W] + pl[ip1 * W]) + GW0 * pl[i * W];
}

// ---------------- gradients + soft clamp + warp + blend ----------------
__global__ void final_k(const float* __restrict__ psis, const float* __restrict__ img,
                        float* __restrict__ osrc, float* __restrict__ oax,
                        float* __restrict__ oay, int Bc) {
    int n = blockIdx.x * 256 + threadIdx.x;
    if (n >= Bc * HW) return;
    int rem = n & (HW - 1);
    int i = rem >> 7;
    int j = rem & 127;
    const float* pl = psis + (n - rem);

    float gx;
    if (j == 0)        gx = pl[i * W + 1] - pl[i * W];
    else if (j == 127) gx = pl[i * W + 127] - pl[i * W + 126];
    else               gx = (pl[i * W + j + 1] - pl[i * W + j - 1]) * 0.5f;
    gx *= 63.5f;  // 1/dx, dx = 2/127

    float gy;
    if (i == 0)        gy = pl[W + j] - pl[j];
    else if (i == 127) gy = pl[127 * W + j] - pl[126 * W + j];
    else               gy = (pl[(i + 1) * W + j] - pl[(i - 1) * W + j]) * 0.5f;
    gy *= 63.5f;

    float ax = 0.5f * tanhf(gx * 2.f);
    float ay = 0.5f * tanhf(gy * 2.f);

    float X = -1.f + 2.f * j / 127.f;
    float Y = -1.f + 2.f * i / 127.f;
    float bx = fminf(fmaxf(X - ax, -1.f), 1.f);
    float by = fminf(fmaxf(Y - ay, -1.f), 1.f);
    float px = (bx + 1.f) * 0.5f * 127.f;
    float py = (by + 1.f) * 0.5f * 127.f;
    float x0f = floorf(px), y0f = floorf(py);
    float wx = px - x0f, wy = py - y0f;
    int x0i = min(max((int)x0f, 0), 127);
    int x1i = min(x0i + 1, 127);
    int y0i = min(max((int)y0f, 0), 127);
    int y1i = min(y0i + 1, 127);

    const float* im = img + (size_t)(n >> 14) * HW;
    float v00 = im[y0i * W + x0i], v01 = im[y0i * W + x1i];
    float v10 = im[y1i * W + x0i], v11 = im[y1i * W + x1i];
    float wrp = v00 * (1.f - wx) * (1.f - wy) + v01 * wx * (1.f - wy) +
                v10 * (1.f - wx) * wy + v11 * wx * wy;

    osrc[n] = 0.9f * wrp + 0.1f * im[rem];
    oax[n]  = ax;
    oay[n]  = ay;
}

// ---------------- launch ----------------
extern "C" void kernel_launch(void* const* d_in, const int* in_sizes, int n_in,
                              void* d_out, int out_size, void* d_ws, size_t ws_size,
                              hipStream_t stream) {
    const float* img = (const float*)d_in[0];
    const int B = in_sizes[0] / HW;  // 64
    const int npix = B * HW;

    float* ws = (float*)d_ws;

    // fixed small allocations at the head: blur tmp, psi_s, transposed weights
    size_t off = 0;
    float* tmp  = ws + off; off += (size_t)B * HW;
    float* psis = ws + off; off += (size_t)B * HW;
    float* wt1  = ws + off; off += 32 * 4 * 9;
    float* wt2  = ws + off; off += 32 * 32 * 9;
    float* wt3  = ws + off; off += 16 * 32 * 9;
    float* wtp1 = ws + off; off += 16 * 4 * 9;
    float* wtp2 = ws + off; off += 16 * 16 * 9;
    size_t head = off;

    // choose batch chunk size that fits workspace: per-chunk need (4+32+32)*BC*HW floats
    int BC = 64;
    while (BC > 2) {
        size_t need = head + (size_t)(4 + 32 + 32) * BC * HW;
        if (need * sizeof(float) <= ws_size) break;
        BC >>= 1;
    }

    float* xbuf = ws + head;
    float* A    = xbuf + (size_t)4 * BC * HW;
    float* Bb   = A + (size_t)32 * BC * HW;
    float* h3   = A;                          // first 16 planes of A
    float* p2   = A + (size_t)16 * BC * HW;   // second 16 planes of A

    float* outsrc = (float*)d_out;
    float* outk   = outsrc + (size_t)B * HW;
    float* outpsi = outk + (size_t)B * HW;
    float* outax  = outpsi + (size_t)B * HW;
    float* outay  = outax + (size_t)B * HW;

    // weight transposes
    wtrans_k<<<4, 256, 0, stream>>>((const float*)d_in[1], wt1, 4, 32);
    wtrans_k<<<16, 256, 0, stream>>>((const float*)d_in[5], wt2, 32, 32);
    wtrans_k<<<8, 256, 0, stream>>>((const float*)d_in[9], wt3, 32, 16);
    wtrans_k<<<2, 256, 0, stream>>>((const float*)d_in[15], wtp1, 4, 16);
    wtrans_k<<<4, 256, 0, stream>>>((const float*)d_in[19], wtp2, 16, 16);

    for (int b0 = 0; b0 < B; b0 += BC) {
        const float* imgc = img + (size_t)b0 * HW;
        int npc = BC * HW;
        int pgrid = (npc + 255) / 256;
        dim3 cgrid(H / 4, BC);

        build_x_k<<<pgrid, 256, 0, stream>>>(imgc, xbuf, BC);

        conv3x3_k<4, 32><<<cgrid, 256, 0, stream>>>(xbuf, wt1, (const float*)d_in[2], A);
        gn_silu_k<32, 8><<<dim3(8, BC), 256, 0, stream>>>(A, (const float*)d_in[3], (const float*)d_in[4]);
        conv3x3_k<32, 32><<<cgrid, 256, 0, stream>>>(A, wt2, (const float*)d_in[6], Bb);
        gn_silu_k<32, 8><<<dim3(8, BC), 256, 0, stream>>>(Bb, (const float*)d_in[7], (const float*)d_in[8]);
        conv3x3_k<32, 16><<<cgrid, 256, 0, stream>>>(Bb, wt3, (const float*)d_in[10], h3);
        gn_silu_k<16, 4><<<dim3(4, BC), 256, 0, stream>>>(h3, (const float*)d_in[11], (const float*)d_in[12]);

        conv3x3_k<4, 16><<<cgrid, 256, 0, stream>>>(xbuf, wtp1, (const float*)d_in[16], Bb);
        gn_silu_k<16, 4><<<dim3(4, BC), 256, 0, stream>>>(Bb, (const float*)d_in[17], (const float*)d_in[18]);
        conv3x3_k<16, 16><<<cgrid, 256, 0, stream>>>(Bb, wtp2, (const float*)d_in[20], p2);
        gn_silu_k<16, 4><<<dim3(4, BC), 256, 0, stream>>>(p2, (const float*)d_in[21], (const float*)d_in[22]);

        psik_k<<<pgrid, 256, 0, stream>>>(h3, p2, (const float*)d_in[13], (const float*)d_in[14],
                                          (const float*)d_in[23], (const float*)d_in[24],
                                          outk + (size_t)b0 * HW, outpsi + (size_t)b0 * HW, BC);
    }

    int pgrid = (npix + 255) / 256;
    blur_h_k<<<pgrid, 256, 0, stream>>>(outpsi, tmp, B);
    blur_v_k<<<pgrid, 256, 0, stream>>>(tmp, psis, B);
    final_k<<<pgrid, 256, 0, stream>>>(psis, img, outsrc, outax, outay, B);
}

// Round 2
// 1200.070 us; speedup vs baseline: 1.1212x; 1.1212x over previous
//
#include <hip/hip_runtime.h>

static constexpr int H = 128, W = 128, HW = H * W;

__device__ __forceinline__ float silu_f(float v) {
    return v / (1.f + __expf(-v));
}

// ---------------- prep: weight transposes + polar planes + zero stats ----------------
// wt layout: [cin][ky][kx][cout]
__global__ void prep_k(const float* __restrict__ w1, const float* __restrict__ w2,
                       const float* __restrict__ w3, const float* __restrict__ wp1,
                       const float* __restrict__ wp2,
                       float* __restrict__ wt1, float* __restrict__ wt2,
                       float* __restrict__ wt3, float* __restrict__ wtp1,
                       float* __restrict__ wtp2,
                       float* __restrict__ polar, float* __restrict__ stats, int nstats) {
    int tid = blockIdx.x * 256 + threadIdx.x;
    int stride = gridDim.x * 256;
    for (int i = tid; i < nstats; i += stride) stats[i] = 0.f;
    for (int i = tid; i < HW; i += stride) {
        int yy = i >> 7, xx = i & 127;
        float X = -1.f + 2.f * xx / 127.f;
        float Y = -1.f + 2.f * yy / 127.f;
        float r = sqrtf(X * X + Y * Y);
        float inv = (r > 0.f) ? 1.f / r : 0.f;
        polar[i]          = r;
        polar[HW + i]     = (r > 0.f) ? X * inv : 1.f;
        polar[2 * HW + i] = Y * inv;
    }
    const float* wsrc[5] = {w1, w2, w3, wp1, wp2};
    float*       wdst[5] = {wt1, wt2, wt3, wtp1, wtp2};
    const int ci[5] = {4, 32, 32, 4, 16};
    const int co[5] = {32, 32, 16, 16, 16};
    for (int s = 0; s < 5; s++) {
        int n = ci[s] * co[s] * 9;
        for (int idx = tid; idx < n; idx += stride) {
            int cout = idx / (ci[s] * 9);
            int rem  = idx - cout * (ci[s] * 9);
            wdst[s][rem * co[s] + cout] = wsrc[s][idx];
        }
    }
}

// ---------------- fused conv3x3 (pad=1) + input-GN+SiLU on load + output GN stats ----------------
// FIRST: input = [img(1 plane per b), polar(3 shared planes)], no input GN.
// else:  input = raw prev conv output [BC][Cin][HW]; apply GN affine + SiLU per load.
// Output: raw conv+bias [BC][Cout][HW]; per-(b,group) sum/sumsq atomically added to stats_out.
template <int Cin, int Cout, int Gin, int Gout, bool FIRST>
__global__ __launch_bounds__(256) void conv_fused_k(
    const float* __restrict__ in, const float* __restrict__ polar,
    const float* __restrict__ wt, const float* __restrict__ bias,
    const float* __restrict__ gin_gamma, const float* __restrict__ gin_beta,
    const float* __restrict__ stats_in,
    float* __restrict__ out, float* __restrict__ stats_out, int b0) {
    const int tid = threadIdx.x;
    const int x0  = (tid & 63) * 2;
    const int y   = blockIdx.x * 4 + (tid >> 6);
    const int b   = blockIdx.y;

    constexpr int GinEff = FIRST ? 1 : Gin;
    float mu[GinEff], rs[GinEff];
    if constexpr (!FIRST) {
        constexpr float inv = 1.f / (float)((Cin / Gin) * HW);
#pragma unroll
        for (int g = 0; g < Gin; g++) {
            float s  = stats_in[((size_t)(b0 + b) * Gin + g) * 2];
            float s2 = stats_in[((size_t)(b0 + b) * Gin + g) * 2 + 1];
            float m  = s * inv;
            mu[g] = m;
            rs[g] = rsqrtf(s2 * inv - m * m + 1e-5f);
        }
    }

    float acc0[Cout], acc1[Cout];
#pragma unroll
    for (int c = 0; c < Cout; c++) { float bv = bias[c]; acc0[c] = bv; acc1[c] = bv; }

    for (int cin = 0; cin < Cin; ++cin) {
        const float* p;
        if constexpr (FIRST) {
            p = (cin == 0) ? in + (size_t)b * HW : polar + (size_t)(cin - 1) * HW;
        } else {
            p = in + ((size_t)b * Cin + cin) * HW;
        }
        float a_c = 1.f, c_c = 0.f;
        if constexpr (!FIRST) {
            int g = cin / (Cin / Gin);
            a_c = gin_gamma[cin] * rs[g];
            c_c = gin_beta[cin] - mu[g] * a_c;
        }
#pragma unroll
        for (int ky = 0; ky < 3; ++ky) {
            int yy = y + ky - 1;
            float v0, v1, v2, v3;
            if (yy < 0 || yy >= H) {
                v0 = v1 = v2 = v3 = 0.f;
            } else {
                const float* row = p + yy * W;
                float r0 = (x0 > 0) ? row[x0 - 1] : 0.f;
                float r1 = row[x0];
                float r2 = row[x0 + 1];
                float r3 = (x0 + 2 < W) ? row[x0 + 2] : 0.f;
                if constexpr (!FIRST) {
                    r0 = (x0 > 0) ? silu_f(fmaf(r0, a_c, c_c)) : 0.f;
                    r1 = silu_f(fmaf(r1, a_c, c_c));
                    r2 = silu_f(fmaf(r2, a_c, c_c));
                    r3 = (x0 + 2 < W) ? silu_f(fmaf(r3, a_c, c_c)) : 0.f;
                }
                v0 = r0; v1 = r1; v2 = r2; v3 = r3;
            }
            const float* wrow = wt + (cin * 9 + ky * 3) * Cout;
#pragma unroll
            for (int c = 0; c < Cout; c++) {
                float w0 = wrow[c];
                float w1 = wrow[Cout + c];
                float w2 = wrow[2 * Cout + c];
                acc0[c] = fmaf(w0, v0, acc0[c]);
                acc0[c] = fmaf(w1, v1, acc0[c]);
                acc0[c] = fmaf(w2, v2, acc0[c]);
                acc1[c] = fmaf(w0, v1, acc1[c]);
                acc1[c] = fmaf(w1, v2, acc1[c]);
                acc1[c] = fmaf(w2, v3, acc1[c]);
            }
        }
    }

    float* ob = out + ((size_t)b * Cout) * HW + y * W + x0;
#pragma unroll
    for (int c = 0; c < Cout; c++) {
        *reinterpret_cast<float2*>(ob + (size_t)c * HW) = make_float2(acc0[c], acc1[c]);
    }

    // output group stats: per-thread partial -> wave shuffle -> LDS -> atomicAdd
    constexpr int CgO = Cout / Gout;
    __shared__ float sdata[4][Gout][2];
    const int lane = tid & 63, wid = tid >> 6;
#pragma unroll
    for (int g = 0; g < Gout; g++) {
        float s = 0.f, s2 = 0.f;
#pragma unroll
        for (int c = g * CgO; c < (g + 1) * CgO; c++) {
            s  += acc0[c] + acc1[c];
            s2 += acc0[c] * acc0[c] + acc1[c] * acc1[c];
        }
#pragma unroll
        for (int off = 32; off > 0; off >>= 1) {
            s  += __shfl_down(s, off);
            s2 += __shfl_down(s2, off);
        }
        if (lane == 0) { sdata[wid][g][0] = s; sdata[wid][g][1] = s2; }
    }
    __syncthreads();
    if (tid < Gout) {
        float s  = sdata[0][tid][0] + sdata[1][tid][0] + sdata[2][tid][0] + sdata[3][tid][0];
        float s2 = sdata[0][tid][1] + sdata[1][tid][1] + sdata[2][tid][1] + sdata[3][tid][1];
        atomicAdd(&stats_out[((size_t)(b0 + b) * Gout + tid) * 2], s);
        atomicAdd(&stats_out[((size_t)(b0 + b) * Gout + tid) * 2 + 1], s2);
    }
}

// ---------------- fused: GN+SiLU on h3/p2 loads + both 1x1 convs -> k, psi ----------------
__global__ void psik_k(const float* __restrict__ h3, const float* __restrict__ p2,
                       const float* __restrict__ kg3, const float* __restrict__ kbeta3,
                       const float* __restrict__ st3,
                       const float* __restrict__ pg2, const float* __restrict__ pbeta2,
                       const float* __restrict__ stp2,
                       const float* __restrict__ kw4, const float* __restrict__ kb4,
                       const float* __restrict__ pw3, const float* __restrict__ pb3,
                       float* __restrict__ outk, float* __restrict__ outpsi,
                       int b0, int Bc) {
    int n = blockIdx.x * 256 + threadIdx.x;
    if (n >= Bc * HW) return;
    int b = n >> 14;
    int rem = n & (HW - 1);
    int i = rem >> 7;
    int j = rem & 127;

    constexpr float inv = 1.f / (float)(4 * HW);  // Cg=4 for both 16ch/4g tensors
    float mu3[4], rs3[4], mup[4], rsp[4];
#pragma unroll
    for (int g = 0; g < 4; g++) {
        float s  = st3[((size_t)(b0 + b) * 4 + g) * 2];
        float s2 = st3[((size_t)(b0 + b) * 4 + g) * 2 + 1];
        float m = s * inv;
        mu3[g] = m; rs3[g] = rsqrtf(s2 * inv - m * m + 1e-5f);
        s  = stp2[((size_t)(b0 + b) * 4 + g) * 2];
        s2 = stp2[((size_t)(b0 + b) * 4 + g) * 2 + 1];
        m = s * inv;
        mup[g] = m; rsp[g] = rsqrtf(s2 * inv - m * m + 1e-5f);
    }

    const float* hb = h3 + (size_t)b * 16 * HW + rem;
    const float* pb = p2 + (size_t)b * 16 * HW + rem;
    float dk = kb4[0], dp = pb3[0];
#pragma unroll
    for (int c = 0; c < 16; c++) {
        int g = c >> 2;
        float a = kg3[c] * rs3[g];
        float t = fmaf(hb[(size_t)c * HW], a, kbeta3[c] - mu3[g] * a);
        dk = fmaf(kw4[c], silu_f(t), dk);
        a = pg2[c] * rsp[g];
        t = fmaf(pb[(size_t)c * HW], a, pbeta2[c] - mup[g] * a);
        dp = fmaf(pw3[c], silu_f(t), dp);
    }
    float k   = 0.5f * (1.f + 0.3f * tanhf(dk));
    float psr = 0.05f * tanhf(dp);
    float X = -1.f + 2.f * j / 127.f;
    float Y = -1.f + 2.f * i / 127.f;
    float r = sqrtf(X * X + Y * Y);
    int nabs = (b0 + b) * HW + rem;
    outk[nabs]   = k;
    outpsi[nabs] = fmaf(k, r, psr);
}

// ---------------- separable gaussian blur, reflect padding ----------------
static __device__ __constant__ float GW0 = 0.40261994689423467f;
static __device__ __constant__ float GW1 = 0.24420134200323348f;
static __device__ __constant__ float GW2 = 0.05448868454964433f;

__global__ void blur_h_k(const float* __restrict__ in, float* __restrict__ out, int Bc) {
    int n = blockIdx.x * 256 + threadIdx.x;
    if (n >= Bc * HW) return;
    int j = n & 127;
    const float* row = in + (n - j);
    int jm2 = j - 2; jm2 = jm2 < 0 ? -jm2 : jm2;
    int jm1 = j - 1; jm1 = jm1 < 0 ? -jm1 : jm1;
    int jp1 = j + 1; jp1 = jp1 > 127 ? 254 - jp1 : jp1;
    int jp2 = j + 2; jp2 = jp2 > 127 ? 254 - jp2 : jp2;
    out[n] = GW2 * (row[jm2] + row[jp2]) + GW1 * (row[jm1] + row[jp1]) + GW0 * row[j];
}

__global__ void blur_v_k(const float* __restrict__ in, float* __restrict__ out, int Bc) {
    int n = blockIdx.x * 256 + threadIdx.x;
    if (n >= Bc * HW) return;
    int rem = n & (HW - 1);
    int i = rem >> 7;
    int j = rem & 127;
    const float* pl = in + (n - rem) + j;
    int im2 = i - 2; im2 = im2 < 0 ? -im2 : im2;
    int im1 = i - 1; im1 = im1 < 0 ? -im1 : im1;
    int ip1 = i + 1; ip1 = ip1 > 127 ? 254 - ip1 : ip1;
    int ip2 = i + 2; ip2 = ip2 > 127 ? 254 - ip2 : ip2;
    out[n] = GW2 * (pl[im2 * W] + pl[ip2 * W]) + GW1 * (pl[im1 * W] + pl[ip1 * W]) + GW0 * pl[i * W];
}

// ---------------- gradients + soft clamp + warp + blend ----------------
__global__ void final_k(const float* __restrict__ psis, const float* __restrict__ img,
                        float* __restrict__ osrc, float* __restrict__ oax,
                        float* __restrict__ oay, int Bc) {
    int n = blockIdx.x * 256 + threadIdx.x;
    if (n >= Bc * HW) return;
    int rem = n & (HW - 1);
    int i = rem >> 7;
    int j = rem & 127;
    const float* pl = psis + (n - rem);

    float gx;
    if (j == 0)        gx = pl[i * W + 1] - pl[i * W];
    else if (j == 127) gx = pl[i * W + 127] - pl[i * W + 126];
    else               gx = (pl[i * W + j + 1] - pl[i * W + j - 1]) * 0.5f;
    gx *= 63.5f;

    float gy;
    if (i == 0)        gy = pl[W + j] - pl[j];
    else if (i == 127) gy = pl[127 * W + j] - pl[126 * W + j];
    else               gy = (pl[(i + 1) * W + j] - pl[(i - 1) * W + j]) * 0.5f;
    gy *= 63.5f;

    float ax = 0.5f * tanhf(gx * 2.f);
    float ay = 0.5f * tanhf(gy * 2.f);

    float X = -1.f + 2.f * j / 127.f;
    float Y = -1.f + 2.f * i / 127.f;
    float bx = fminf(fmaxf(X - ax, -1.f), 1.f);
    float by = fminf(fmaxf(Y - ay, -1.f), 1.f);
    float px = (bx + 1.f) * 0.5f * 127.f;
    float py = (by + 1.f) * 0.5f * 127.f;
    float x0f = floorf(px), y0f = floorf(py);
    float wx = px - x0f, wy = py - y0f;
    int x0i = min(max((int)x0f, 0), 127);
    int x1i = min(x0i + 1, 127);
    int y0i = min(max((int)y0f, 0), 127);
    int y1i = min(y0i + 1, 127);

    const float* im = img + (size_t)(n >> 14) * HW;
    float v00 = im[y0i * W + x0i], v01 = im[y0i * W + x1i];
    float v10 = im[y1i * W + x0i], v11 = im[y1i * W + x1i];
    float wrp = v00 * (1.f - wx) * (1.f - wy) + v01 * wx * (1.f - wy) +
                v10 * (1.f - wx) * wy + v11 * wx * wy;

    osrc[n] = 0.9f * wrp + 0.1f * im[rem];
    oax[n]  = ax;
    oay[n]  = ay;
}

// ---------------- launch ----------------
extern "C" void kernel_launch(void* const* d_in, const int* in_sizes, int n_in,
                              void* d_out, int out_size, void* d_ws, size_t ws_size,
                              hipStream_t stream) {
    const float* img = (const float*)d_in[0];
    const int B = in_sizes[0] / HW;  // 64
    const int npix = B * HW;

    float* ws = (float*)d_ws;

    size_t off = 0;
    float* tmp   = ws + off; off += (size_t)B * HW;
    float* psis  = ws + off; off += (size_t)B * HW;
    float* polar = ws + off; off += 3 * HW;
    float* wt1   = ws + off; off += 32 * 4 * 9;
    float* wt2   = ws + off; off += 32 * 32 * 9;
    float* wt3   = ws + off; off += 16 * 32 * 9;
    float* wtp1  = ws + off; off += 16 * 4 * 9;
    float* wtp2  = ws + off; off += 16 * 16 * 9;
    float* stats = ws + off;
    float* st1  = stats;            // B*8*2
    float* st2  = st1 + (size_t)B * 16;
    float* st3  = st2 + (size_t)B * 16;  // B*4*2
    float* stp1 = st3 + (size_t)B * 8;
    float* stp2 = stp1 + (size_t)B * 8;
    int nstats = B * 16 * 2 + B * 8 * 3;
    off += nstats;
    size_t head = off;

    // per-chunk: A(32 planes) + Bb(32 planes)
    int BC = B;
    while (BC > 2) {
        size_t need = head + (size_t)64 * BC * HW;
        if (need * sizeof(float) <= ws_size) break;
        BC >>= 1;
    }

    float* A  = ws + head;
    float* Bb = A + (size_t)32 * BC * HW;
    float* h3 = A;                        // [BC][16][HW]
    float* p2 = A + (size_t)16 * BC * HW; // [BC][16][HW]

    float* outsrc = (float*)d_out;
    float* outk   = outsrc + (size_t)B * HW;
    float* outpsi = outk + (size_t)B * HW;
    float* outax  = outpsi + (size_t)B * HW;
    float* outay  = outax + (size_t)B * HW;

    prep_k<<<64, 256, 0, stream>>>((const float*)d_in[1], (const float*)d_in[5],
                                   (const float*)d_in[9], (const float*)d_in[15],
                                   (const float*)d_in[19],
                                   wt1, wt2, wt3, wtp1, wtp2, polar, stats, nstats);

    for (int b0 = 0; b0 < B; b0 += BC) {
        const float* imgc = img + (size_t)b0 * HW;
        int npc = BC * HW;
        int pgrid = (npc + 255) / 256;
        dim3 cgrid(H / 4, BC);

        conv_fused_k<4, 32, 1, 8, true><<<cgrid, 256, 0, stream>>>(
            imgc, polar, wt1, (const float*)d_in[2], nullptr, nullptr, nullptr, A, st1, b0);
        conv_fused_k<32, 32, 8, 8, false><<<cgrid, 256, 0, stream>>>(
            A, nullptr, wt2, (const float*)d_in[6], (const float*)d_in[3],
            (const float*)d_in[4], st1, Bb, st2, b0);
        conv_fused_k<32, 16, 8, 4, false><<<cgrid, 256, 0, stream>>>(
            Bb, nullptr, wt3, (const float*)d_in[10], (const float*)d_in[7],
            (const float*)d_in[8], st2, h3, st3, b0);

        conv_fused_k<4, 16, 1, 4, true><<<cgrid, 256, 0, stream>>>(
            imgc, polar, wtp1, (const float*)d_in[16], nullptr, nullptr, nullptr, Bb, stp1, b0);
        conv_fused_k<16, 16, 4, 4, false><<<cgrid, 256, 0, stream>>>(
            Bb, nullptr, wtp2, (const float*)d_in[20], (const float*)d_in[17],
            (const float*)d_in[18], stp1, p2, stp2, b0);

        psik_k<<<pgrid, 256, 0, stream>>>(h3, p2,
                                          (const float*)d_in[11], (const float*)d_in[12], st3,
                                          (const float*)d_in[21], (const float*)d_in[22], stp2,
                                          (const float*)d_in[13], (const float*)d_in[14],
                                          (const float*)d_in[23], (const float*)d_in[24],
                                          outk, outpsi, b0, BC);
    }

    int pgrid = (npix + 255) / 256;
    blur_h_k<<<pgrid, 256, 0, stream>>>(outpsi, tmp, B);
    blur_v_k<<<pgrid, 256, 0, stream>>>(tmp, psis, B);
    final_k<<<pgrid, 256, 0, stream>>>(psis, img, outsrc, outax, outay, B);
}

// Round 3
// 992.953 us; speedup vs baseline: 1.3551x; 1.2086x over previous
//
#include <hip/hip_runtime.h>

static constexpr int H = 128, W = 128, HW = H * W;

__device__ __forceinline__ float silu_f(float v) {
    return v / (1.f + __expf(-v));
}

// ---------------- prep: weight transposes + polar planes + zero stats ----------------
__global__ void prep_k(const float* __restrict__ w1, const float* __restrict__ w2,
                       const float* __restrict__ w3, const float* __restrict__ wp1,
                       const float* __restrict__ wp2,
                       float* __restrict__ wt1, float* __restrict__ wt2,
                       float* __restrict__ wt3, float* __restrict__ wtp1,
                       float* __restrict__ wtp2,
                       float* __restrict__ polar, float* __restrict__ stats, int nstats) {
    int tid = blockIdx.x * 256 + threadIdx.x;
    int stride = gridDim.x * 256;
    for (int i = tid; i < nstats; i += stride) stats[i] = 0.f;
    for (int i = tid; i < HW; i += stride) {
        int yy = i >> 7, xx = i & 127;
        float X = -1.f + 2.f * xx / 127.f;
        float Y = -1.f + 2.f * yy / 127.f;
        float r = sqrtf(X * X + Y * Y);
        float inv = (r > 0.f) ? 1.f / r : 0.f;
        polar[i]          = r;
        polar[HW + i]     = (r > 0.f) ? X * inv : 1.f;
        polar[2 * HW + i] = Y * inv;
    }
    const float* wsrc[5] = {w1, w2, w3, wp1, wp2};
    float*       wdst[5] = {wt1, wt2, wt3, wtp1, wtp2};
    const int ci[5] = {4, 32, 32, 4, 16};
    const int co[5] = {32, 32, 16, 16, 16};
    for (int s = 0; s < 5; s++) {
        int n = ci[s] * co[s] * 9;
        for (int idx = tid; idx < n; idx += stride) {
            int cout = idx / (ci[s] * 9);
            int rem  = idx - cout * (ci[s] * 9);
            wdst[s][rem * co[s] + cout] = wsrc[s][idx];
        }
    }
}

// ---------------- conv3x3 v3: 1 px/thread, LDS-staged input, GN+SiLU once per element ----------------
// Block: 512 threads, tile = 4 rows x 128 cols, all Cout accumulated in registers.
// FIRST: input = [img plane, 3 shared polar planes], no input GN.
// else : input = raw prev conv output; GN affine+SiLU applied once at LDS-stage time.
// Output: raw conv+bias; per-(b,group) sum/sumsq atomically added to stats_out.
template <int Cin, int Cout, int Gin, int Gout, bool FIRST>
__global__ __launch_bounds__(512) void conv_v3_k(
    const float* __restrict__ in, const float* __restrict__ polar,
    const float* __restrict__ wt, const float* __restrict__ bias,
    const float* __restrict__ gin_gamma, const float* __restrict__ gin_beta,
    const float* __restrict__ stats_in,
    float* __restrict__ out, float* __restrict__ stats_out, int b0) {
    constexpr int CHUNK = (Cin < 8) ? Cin : 8;
    constexpr int NCH = Cin / CHUNK;
    __shared__ float tile[CHUNK][6][128];
    __shared__ float lds_a[FIRST ? 1 : Cin];
    __shared__ float lds_c[FIRST ? 1 : Cin];
    __shared__ float sred[8][Gout][2];

    const int tid   = threadIdx.x;
    const int b     = blockIdx.y;
    const int y0    = blockIdx.x * 4;
    const int r_out = tid >> 7;   // 0..3
    const int col   = tid & 127;

    if constexpr (!FIRST) {
        if (tid < Cin) {
            constexpr float inv = 1.f / ((Cin / Gin) * (float)HW);
            int g = tid / (Cin / Gin);
            float s  = stats_in[((size_t)(b0 + b) * Gin + g) * 2];
            float s2 = stats_in[((size_t)(b0 + b) * Gin + g) * 2 + 1];
            float m  = s * inv;
            float rs = rsqrtf(s2 * inv - m * m + 1e-5f);
            float a  = gin_gamma[tid] * rs;
            lds_a[tid] = a;
            lds_c[tid] = gin_beta[tid] - m * a;
        }
    }

    float acc[Cout];
#pragma unroll
    for (int c = 0; c < Cout; c++) acc[c] = bias[c];

    for (int ch = 0; ch < NCH; ch++) {
        __syncthreads();   // also orders lds_a writes before first stage
#pragma unroll
        for (int e = 0; e < CHUNK * 768 / 512; e++) {
            int idx = tid + e * 512;
            int cl  = idx / 768;
            int rr  = (idx % 768) / 128;
            int cc  = idx & 127;
            int cin = ch * CHUNK + cl;
            int yy  = y0 - 1 + rr;
            float v = 0.f;
            if (yy >= 0 && yy < H) {
                const float* p;
                if constexpr (FIRST)
                    p = (cin == 0) ? in + (size_t)b * HW : polar + (size_t)(cin - 1) * HW;
                else
                    p = in + ((size_t)b * Cin + cin) * HW;
                v = p[yy * W + cc];
                if constexpr (!FIRST)
                    v = silu_f(fmaf(v, lds_a[cin], lds_c[cin]));
            }
            tile[cl][rr][cc] = v;
        }
        __syncthreads();
        for (int cl = 0; cl < CHUNK; cl++) {
            const float* wbase = wt + ((size_t)(ch * CHUNK + cl)) * 9 * Cout;
#pragma unroll
            for (int ky = 0; ky < 3; ky++) {
                const float* t = &tile[cl][r_out + ky][0];
                float v1 = t[col];
                float v0 = (col > 0)   ? t[col - 1] : 0.f;
                float v2 = (col < 127) ? t[col + 1] : 0.f;
                const float* wr = wbase + ky * 3 * Cout;
#pragma unroll
                for (int c = 0; c < Cout; c++) {
                    acc[c] = fmaf(wr[c], v0, acc[c]);
                    acc[c] = fmaf(wr[Cout + c], v1, acc[c]);
                    acc[c] = fmaf(wr[2 * Cout + c], v2, acc[c]);
                }
            }
        }
    }

    float* ob = out + ((size_t)b * Cout) * HW + (y0 + r_out) * W + col;
#pragma unroll
    for (int c = 0; c < Cout; c++) ob[(size_t)c * HW] = acc[c];

    // ---- output group stats ----
    constexpr int CgO = Cout / Gout;
    const int lane = tid & 63, wid = tid >> 6;
#pragma unroll
    for (int g = 0; g < Gout; g++) {
        float s = 0.f, s2 = 0.f;
#pragma unroll
        for (int c = g * CgO; c < (g + 1) * CgO; c++) { s += acc[c]; s2 += acc[c] * acc[c]; }
#pragma unroll
        for (int off = 32; off > 0; off >>= 1) {
            s  += __shfl_down(s, off);
            s2 += __shfl_down(s2, off);
        }
        if (lane == 0) { sred[wid][g][0] = s; sred[wid][g][1] = s2; }
    }
    __syncthreads();
    if (tid < Gout) {
        float s = 0.f, s2 = 0.f;
#pragma unroll
        for (int w = 0; w < 8; w++) { s += sred[w][tid][0]; s2 += sred[w][tid][1]; }
        atomicAdd(&stats_out[((size_t)(b0 + b) * Gout + tid) * 2], s);
        atomicAdd(&stats_out[((size_t)(b0 + b) * Gout + tid) * 2 + 1], s2);
    }
}

// ---------------- fused: GN+SiLU on h3/p2 loads + both 1x1 convs -> k, psi ----------------
__global__ void psik_k(const float* __restrict__ h3, const float* __restrict__ p2,
                       const float* __restrict__ kg3, const float* __restrict__ kbeta3,
                       const float* __restrict__ st3,
                       const float* __restrict__ pg2, const float* __restrict__ pbeta2,
                       const float* __restrict__ stp2,
                       const float* __restrict__ kw4, const float* __restrict__ kb4,
                       const float* __restrict__ pw3, const float* __restrict__ pb3,
                       float* __restrict__ outk, float* __restrict__ outpsi,
                       int b0, int Bc) {
    int n = blockIdx.x * 256 + threadIdx.x;
    if (n >= Bc * HW) return;
    int b = n >> 14;
    int rem = n & (HW - 1);
    int i = rem >> 7;
    int j = rem & 127;

    constexpr float inv = 1.f / (float)(4 * HW);
    float mu3[4], rs3[4], mup[4], rsp[4];
#pragma unroll
    for (int g = 0; g < 4; g++) {
        float s  = st3[((size_t)(b0 + b) * 4 + g) * 2];
        float s2 = st3[((size_t)(b0 + b) * 4 + g) * 2 + 1];
        float m = s * inv;
        mu3[g] = m; rs3[g] = rsqrtf(s2 * inv - m * m + 1e-5f);
        s  = stp2[((size_t)(b0 + b) * 4 + g) * 2];
        s2 = stp2[((size_t)(b0 + b) * 4 + g) * 2 + 1];
        m = s * inv;
        mup[g] = m; rsp[g] = rsqrtf(s2 * inv - m * m + 1e-5f);
    }

    const float* hb = h3 + (size_t)b * 16 * HW + rem;
    const float* pb = p2 + (size_t)b * 16 * HW + rem;
    float dk = kb4[0], dp = pb3[0];
#pragma unroll
    for (int c = 0; c < 16; c++) {
        int g = c >> 2;
        float a = kg3[c] * rs3[g];
        float t = fmaf(hb[(size_t)c * HW], a, kbeta3[c] - mu3[g] * a);
        dk = fmaf(kw4[c], silu_f(t), dk);
        a = pg2[c] * rsp[g];
        t = fmaf(pb[(size_t)c * HW], a, pbeta2[c] - mup[g] * a);
        dp = fmaf(pw3[c], silu_f(t), dp);
    }
    float k   = 0.5f * (1.f + 0.3f * tanhf(dk));
    float psr = 0.05f * tanhf(dp);
    float X = -1.f + 2.f * j / 127.f;
    float Y = -1.f + 2.f * i / 127.f;
    float r = sqrtf(X * X + Y * Y);
    int nabs = (b0 + b) * HW + rem;
    outk[nabs]   = k;
    outpsi[nabs] = fmaf(k, r, psr);
}

// ---------------- separable gaussian blur, reflect padding ----------------
static __device__ __constant__ float GW0 = 0.40261994689423467f;
static __device__ __constant__ float GW1 = 0.24420134200323348f;
static __device__ __constant__ float GW2 = 0.05448868454964433f;

__global__ void blur_h_k(const float* __restrict__ in, float* __restrict__ out, int Bc) {
    int n = blockIdx.x * 256 + threadIdx.x;
    if (n >= Bc * HW) return;
    int j = n & 127;
    const float* row = in + (n - j);
    int jm2 = j - 2; jm2 = jm2 < 0 ? -jm2 : jm2;
    int jm1 = j - 1; jm1 = jm1 < 0 ? -jm1 : jm1;
    int jp1 = j + 1; jp1 = jp1 > 127 ? 254 - jp1 : jp1;
    int jp2 = j + 2; jp2 = jp2 > 127 ? 254 - jp2 : jp2;
    out[n] = GW2 * (row[jm2] + row[jp2]) + GW1 * (row[jm1] + row[jp1]) + GW0 * row[j];
}

__global__ void blur_v_k(const float* __restrict__ in, float* __restrict__ out, int Bc) {
    int n = blockIdx.x * 256 + threadIdx.x;
    if (n >= Bc * HW) return;
    int rem = n & (HW - 1);
    int i = rem >> 7;
    int j = rem & 127;
    const float* pl = in + (n - rem) + j;
    int im2 = i - 2; im2 = im2 < 0 ? -im2 : im2;
    int im1 = i - 1; im1 = im1 < 0 ? -im1 : im1;
    int ip1 = i + 1; ip1 = ip1 > 127 ? 254 - ip1 : ip1;
    int ip2 = i + 2; ip2 = ip2 > 127 ? 254 - ip2 : ip2;
    out[n] = GW2 * (pl[im2 * W] + pl[ip2 * W]) + GW1 * (pl[im1 * W] + pl[ip1 * W]) + GW0 * pl[i * W];
}

// ---------------- gradients + soft clamp + warp + blend ----------------
__global__ void final_k(const float* __restrict__ psis, const float* __restrict__ img,
                        float* __restrict__ osrc, float* __restrict__ oax,
                        float* __restrict__ oay, int Bc) {
    int n = blockIdx.x * 256 + threadIdx.x;
    if (n >= Bc * HW) return;
    int rem = n & (HW - 1);
    int i = rem >> 7;
    int j = rem & 127;
    const float* pl = psis + (n - rem);

    float gx;
    if (j == 0)        gx = pl[i * W + 1] - pl[i * W];
    else if (j == 127) gx = pl[i * W + 127] - pl[i * W + 126];
    else               gx = (pl[i * W + j + 1] - pl[i * W + j - 1]) * 0.5f;
    gx *= 63.5f;

    float gy;
    if (i == 0)        gy = pl[W + j] - pl[j];
    else if (i == 127) gy = pl[127 * W + j] - pl[126 * W + j];
    else               gy = (pl[(i + 1) * W + j] - pl[(i - 1) * W + j]) * 0.5f;
    gy *= 63.5f;

    float ax = 0.5f * tanhf(gx * 2.f);
    float ay = 0.5f * tanhf(gy * 2.f);

    float X = -1.f + 2.f * j / 127.f;
    float Y = -1.f + 2.f * i / 127.f;
    float bx = fminf(fmaxf(X - ax, -1.f), 1.f);
    float by = fminf(fmaxf(Y - ay, -1.f), 1.f);
    float px = (bx + 1.f) * 0.5f * 127.f;
    float py = (by + 1.f) * 0.5f * 127.f;
    float x0f = floorf(px), y0f = floorf(py);
    float wx = px - x0f, wy = py - y0f;
    int x0i = min(max((int)x0f, 0), 127);
    int x1i = min(x0i + 1, 127);
    int y0i = min(max((int)y0f, 0), 127);
    int y1i = min(y0i + 1, 127);

    const float* im = img + (size_t)(n >> 14) * HW;
    float v00 = im[y0i * W + x0i], v01 = im[y0i * W + x1i];
    float v10 = im[y1i * W + x0i], v11 = im[y1i * W + x1i];
    float wrp = v00 * (1.f - wx) * (1.f - wy) + v01 * wx * (1.f - wy) +
                v10 * (1.f - wx) * wy + v11 * wx * wy;

    osrc[n] = 0.9f * wrp + 0.1f * im[rem];
    oax[n]  = ax;
    oay[n]  = ay;
}

// ---------------- launch ----------------
extern "C" void kernel_launch(void* const* d_in, const int* in_sizes, int n_in,
                              void* d_out, int out_size, void* d_ws, size_t ws_size,
                              hipStream_t stream) {
    const float* img = (const float*)d_in[0];
    const int B = in_sizes[0] / HW;  // 64
    const int npix = B * HW;

    float* ws = (float*)d_ws;

    size_t off = 0;
    float* tmp   = ws + off; off += (size_t)B * HW;
    float* psis  = ws + off; off += (size_t)B * HW;
    float* polar = ws + off; off += 3 * HW;
    float* wt1   = ws + off; off += 32 * 4 * 9;
    float* wt2   = ws + off; off += 32 * 32 * 9;
    float* wt3   = ws + off; off += 16 * 32 * 9;
    float* wtp1  = ws + off; off += 16 * 4 * 9;
    float* wtp2  = ws + off; off += 16 * 16 * 9;
    float* stats = ws + off;
    float* st1  = stats;                  // B*8*2
    float* st2  = st1 + (size_t)B * 16;   // B*8*2
    float* st3  = st2 + (size_t)B * 16;   // B*4*2
    float* stp1 = st3 + (size_t)B * 8;    // B*4*2
    float* stp2 = stp1 + (size_t)B * 8;   // B*4*2
    int nstats = B * 56;
    off += nstats;
    size_t head = off;

    // per-chunk: A(32 planes) + Bb(32 planes)
    int BC = B;
    while (BC > 2) {
        size_t need = head + (size_t)64 * BC * HW;
        if (need * sizeof(float) <= ws_size) break;
        BC >>= 1;
    }

    float* A  = ws + head;
    float* Bb = A + (size_t)32 * BC * HW;
    float* h3 = A;                        // [BC][16][HW]
    float* p2 = A + (size_t)16 * BC * HW; // [BC][16][HW]

    float* outsrc = (float*)d_out;
    float* outk   = outsrc + (size_t)B * HW;
    float* outpsi = outk + (size_t)B * HW;
    float* outax  = outpsi + (size_t)B * HW;
    float* outay  = outax + (size_t)B * HW;

    prep_k<<<64, 256, 0, stream>>>((const float*)d_in[1], (const float*)d_in[5],
                                   (const float*)d_in[9], (const float*)d_in[15],
                                   (const float*)d_in[19],
                                   wt1, wt2, wt3, wtp1, wtp2, polar, stats, nstats);

    for (int b0 = 0; b0 < B; b0 += BC) {
        const float* imgc = img + (size_t)b0 * HW;
        int npc = BC * HW;
        int pgrid = (npc + 255) / 256;
        dim3 cgrid(H / 4, BC);

        conv_v3_k<4, 32, 1, 8, true><<<cgrid, 512, 0, stream>>>(
            imgc, polar, wt1, (const float*)d_in[2], nullptr, nullptr, nullptr, A, st1, b0);
        conv_v3_k<32, 32, 8, 8, false><<<cgrid, 512, 0, stream>>>(
            A, nullptr, wt2, (const float*)d_in[6], (const float*)d_in[3],
            (const float*)d_in[4], st1, Bb, st2, b0);
        conv_v3_k<32, 16, 8, 4, false><<<cgrid, 512, 0, stream>>>(
            Bb, nullptr, wt3, (const float*)d_in[10], (const float*)d_in[7],
            (const float*)d_in[8], st2, h3, st3, b0);

        conv_v3_k<4, 16, 1, 4, true><<<cgrid, 512, 0, stream>>>(
            imgc, polar, wtp1, (const float*)d_in[16], nullptr, nullptr, nullptr, Bb, stp1, b0);
        conv_v3_k<16, 16, 4, 4, false><<<cgrid, 512, 0, stream>>>(
            Bb, nullptr, wtp2, (const float*)d_in[20], (const float*)d_in[17],
            (const float*)d_in[18], stp1, p2, stp2, b0);

        psik_k<<<pgrid, 256, 0, stream>>>(h3, p2,
                                          (const float*)d_in[11], (const float*)d_in[12], st3,
                                          (const float*)d_in[21], (const float*)d_in[22], stp2,
                                          (const float*)d_in[13], (const float*)d_in[14],
                                          (const float*)d_in[23], (const float*)d_in[24],
                                          outk, outpsi, b0, BC);
    }

    int pgrid = (npix + 255) / 256;
    blur_h_k<<<pgrid, 256, 0, stream>>>(outpsi, tmp, B);
    blur_v_k<<<pgrid, 256, 0, stream>>>(tmp, psis, B);
    final_k<<<pgrid, 256, 0, stream>>>(psis, img, outsrc, outax, outay, B);
}